// Round 2
// 1003.134 us; speedup vs baseline: 1.1272x; 1.1272x over previous
//
#include <hip/hip_runtime.h>

#define NN 50000
#define NE 500000
#define HD 128

typedef unsigned short ushort_t;
typedef __bf16 bf16x8 __attribute__((ext_vector_type(8)));
typedef float f32x4 __attribute__((ext_vector_type(4)));
typedef float f32x2 __attribute__((ext_vector_type(2)));  // clang-native vector: valid for nontemporal builtins

static __device__ __forceinline__ unsigned short f2bf(float f) {
  unsigned int u = __float_as_uint(f);
  unsigned int r = (u + 0x7fffu + ((u >> 16) & 1u)) >> 16;  // RNE
  return (unsigned short)r;
}
static __device__ __forceinline__ float2 ldbf2(const unsigned short* p) {
  unsigned int u = *reinterpret_cast<const unsigned int*>(p);
  return make_float2(__uint_as_float(u << 16), __uint_as_float(u & 0xffff0000u));
}

// ---------------- CSR build ----------------
__global__ __launch_bounds__(256) void hist_kernel(const int* __restrict__ src, const int* __restrict__ dst,
                                                   int* __restrict__ deg_src, int* __restrict__ deg_dst, int E) {
  int e = blockIdx.x * 256 + threadIdx.x;
  if (e < E) {
    atomicAdd(&deg_dst[dst[e]], 1);
    atomicAdd(&deg_src[src[e]], 1);
  }
}

__global__ __launch_bounds__(1024) void scan_kernel(const int* __restrict__ deg_dst, const int* __restrict__ deg_src,
                                                    int* __restrict__ off_dst, int* __restrict__ cur_dst,
                                                    int* __restrict__ off_src, int* __restrict__ cur_src, int N) {
  const int* deg = blockIdx.x ? deg_src : deg_dst;
  int* off = blockIdx.x ? off_src : off_dst;
  int* cur = blockIdx.x ? cur_src : cur_dst;
  const int CH = (N + 1023) / 1024;
  int t = threadIdx.x;
  int base = t * CH;
  int sum = 0;
  for (int i = 0; i < CH; ++i) { int idx = base + i; if (idx < N) sum += deg[idx]; }
  __shared__ int ls[1024];
  ls[t] = sum;
  __syncthreads();
  for (int o = 1; o < 1024; o <<= 1) {
    int u = (t >= o) ? ls[t - o] : 0;
    __syncthreads();
    ls[t] += u;
    __syncthreads();
  }
  int run = ls[t] - sum;  // exclusive prefix of this thread's chunk
  for (int i = 0; i < CH; ++i) {
    int idx = base + i;
    if (idx < N) { off[idx] = run; cur[idx] = run; run += deg[idx]; }
  }
  if (t == 1023) off[N] = ls[1023];
}

// Pre-resolve adjacency: agg needs (e, src[e]) per CSR-by-dst slot; attn needs only dst[e] per CSR-by-src slot.
__global__ __launch_bounds__(256) void scatter_kernel(const int* __restrict__ src, const int* __restrict__ dst,
                                                      int* __restrict__ cur_src, int* __restrict__ cur_dst,
                                                      int* __restrict__ adj_src, int2* __restrict__ pair_dst, int E) {
  int e = blockIdx.x * 256 + threadIdx.x;
  if (e < E) {
    int s = src[e], d = dst[e];
    int p = atomicAdd(&cur_dst[d], 1); pair_dst[p] = make_int2(e, s);
    int q = atomicAdd(&cur_src[s], 1); adj_src[q] = d;
  }
}

// ---------------- fp32 -> bf16 convert ----------------
__global__ __launch_bounds__(256) void hconv_kernel(const float* __restrict__ h, ushort_t* __restrict__ hb, int total4) {
  int i = blockIdx.x * 256 + threadIdx.x;
  if (i >= total4) return;
  float4 v = reinterpret_cast<const float4*>(h)[i];
  ushort4 u = { f2bf(v.x), f2bf(v.y), f2bf(v.z), f2bf(v.w) };
  reinterpret_cast<ushort4*>(hb)[i] = u;
}

// ---------------- generic small-K MFMA GEMM: out = epi(A @ W^T + bias) ----------------
// MODE bits: 1 = relu, 2 = add resid (fp32 [nrows,OUTC]), 4 = out is bf16 (else fp32)
template <int K, int OUTC, int MODE>
__global__ __launch_bounds__(256) void gemm_kernel(const ushort_t* __restrict__ A, const float* __restrict__ W,
                                                   const float* __restrict__ bias, const float* __restrict__ resid,
                                                   void* __restrict__ out, float scale, int nrows) {
  constexpr int KP = K + 8;  // +16B pad per row: breaks LDS bank conflicts
  __shared__ __align__(16) ushort_t wlds[OUTC * KP];
  constexpr int NLOAD = OUTC * K / 4;
  for (int idx = threadIdx.x; idx < NLOAD; idx += 256) {
    int r = idx / (K / 4), c4 = idx % (K / 4);
    float4 wv = reinterpret_cast<const float4*>(W)[idx];
    ushort_t* d = &wlds[r * KP + c4 * 4];
    d[0] = f2bf(wv.x); d[1] = f2bf(wv.y); d[2] = f2bf(wv.z); d[3] = f2bf(wv.w);
  }
  __syncthreads();
  const int wave = threadIdx.x >> 6, lane = threadIdx.x & 63;
  const int row0 = (blockIdx.x * 4 + wave) * 16;
  if (row0 >= nrows) return;
  const int m = lane & 15, quad = lane >> 4;
  // A fragments: lane holds A[row0+m][kk*32 + quad*8 + j], j=0..7 (verified m91 layout)
  bf16x8 afrag[K / 32];
  {
    const ushort_t* ar = A + (size_t)(row0 + m) * K + quad * 8;
#pragma unroll
    for (int kk = 0; kk < K / 32; ++kk)
      afrag[kk] = *reinterpret_cast<const bf16x8*>(ar + kk * 32);
  }
  f32x4 acc[OUTC / 16] = {};
#pragma unroll
  for (int c = 0; c < OUTC / 16; ++c) {
    const ushort_t* wr = &wlds[(c * 16 + m) * KP + quad * 8];
#pragma unroll
    for (int kk = 0; kk < K / 32; ++kk) {
      bf16x8 bfrag = *reinterpret_cast<const bf16x8*>(wr + kk * 32);
      acc[c] = __builtin_amdgcn_mfma_f32_16x16x32_bf16(afrag[kk], bfrag, acc[c], 0, 0, 0);
    }
  }
#pragma unroll
  for (int c = 0; c < OUTC / 16; ++c) {
    int col = c * 16 + m;
    float bv = bias[col];
#pragma unroll
    for (int r = 0; r < 4; ++r) {
      int grow = row0 + quad * 4 + r;  // C/D layout: row=(lane>>4)*4+reg, col=lane&15
      float val = (acc[c][r] + bv) * scale;
      if constexpr (MODE & 1) val = fmaxf(val, 0.0f);
      if constexpr (MODE & 2) val += resid[(size_t)grow * OUTC + col];
      if constexpr (MODE & 4) ((ushort_t*)out)[(size_t)grow * OUTC + col] = f2bf(val);
      else ((float*)out)[(size_t)grow * OUTC + col] = val;
    }
  }
}

// ---------------- GINE aggregation + eattr passthrough copy ----------------
// wave-per-node over CSR-by-dst: z = h[n] + sum_e relu(h[src[e]] + eattr[e]); also out_eattr[e] = eattr[e]
// Latency-bound loop: 4-way unroll + software-pipelined pair prefetch -> >=8 loads in flight per wave.
__global__ __launch_bounds__(256) void agg_kernel(const float* __restrict__ h, const float* __restrict__ eattr,
                                                  const int* __restrict__ off_dst, const int2* __restrict__ pair_dst,
                                                  float* __restrict__ out_eattr, ushort_t* __restrict__ z_bf, int N) {
  int wave = threadIdx.x >> 6, lane = threadIdx.x & 63;
  int n = blockIdx.x * 4 + wave;
  if (n >= N) return;
  int c2 = lane * 2;
  float a0 = 0.f, a1 = 0.f;
  int beg = off_dst[n], end = off_dst[n + 1];
  int i = beg;
  int mainend = beg + ((end - beg) & ~3);
  if (i < mainend) {
    int2 p0 = pair_dst[i], p1 = pair_dst[i + 1], p2 = pair_dst[i + 2], p3 = pair_dst[i + 3];
    for (;;) {
      f32x2 ea0 = __builtin_nontemporal_load(reinterpret_cast<const f32x2*>(eattr + (size_t)p0.x * HD + c2));
      f32x2 ea1 = __builtin_nontemporal_load(reinterpret_cast<const f32x2*>(eattr + (size_t)p1.x * HD + c2));
      f32x2 ea2 = __builtin_nontemporal_load(reinterpret_cast<const f32x2*>(eattr + (size_t)p2.x * HD + c2));
      f32x2 ea3 = __builtin_nontemporal_load(reinterpret_cast<const f32x2*>(eattr + (size_t)p3.x * HD + c2));
      f32x2 hs0 = *reinterpret_cast<const f32x2*>(h + (size_t)p0.y * HD + c2);
      f32x2 hs1 = *reinterpret_cast<const f32x2*>(h + (size_t)p1.y * HD + c2);
      f32x2 hs2 = *reinterpret_cast<const f32x2*>(h + (size_t)p2.y * HD + c2);
      f32x2 hs3 = *reinterpret_cast<const f32x2*>(h + (size_t)p3.y * HD + c2);
      int ni = i + 4;
      int pi = (ni < mainend) ? ni : beg;  // safe prefetch address (nmain>=4 guaranteed)
      int2 q0 = pair_dst[pi], q1 = pair_dst[pi + 1], q2 = pair_dst[pi + 2], q3 = pair_dst[pi + 3];
      __builtin_nontemporal_store(ea0, reinterpret_cast<f32x2*>(out_eattr + (size_t)p0.x * HD + c2));
      __builtin_nontemporal_store(ea1, reinterpret_cast<f32x2*>(out_eattr + (size_t)p1.x * HD + c2));
      __builtin_nontemporal_store(ea2, reinterpret_cast<f32x2*>(out_eattr + (size_t)p2.x * HD + c2));
      __builtin_nontemporal_store(ea3, reinterpret_cast<f32x2*>(out_eattr + (size_t)p3.x * HD + c2));
      a0 += (fmaxf(hs0.x + ea0.x, 0.f) + fmaxf(hs1.x + ea1.x, 0.f)) +
            (fmaxf(hs2.x + ea2.x, 0.f) + fmaxf(hs3.x + ea3.x, 0.f));
      a1 += (fmaxf(hs0.y + ea0.y, 0.f) + fmaxf(hs1.y + ea1.y, 0.f)) +
            (fmaxf(hs2.y + ea2.y, 0.f) + fmaxf(hs3.y + ea3.y, 0.f));
      p0 = q0; p1 = q1; p2 = q2; p3 = q3;
      i = ni;
      if (i >= mainend) break;
    }
  }
  for (; i < end; ++i) {
    int2 p = pair_dst[i];
    f32x2 ea = __builtin_nontemporal_load(reinterpret_cast<const f32x2*>(eattr + (size_t)p.x * HD + c2));
    f32x2 hs = *reinterpret_cast<const f32x2*>(h + (size_t)p.y * HD + c2);
    __builtin_nontemporal_store(ea, reinterpret_cast<f32x2*>(out_eattr + (size_t)p.x * HD + c2));
    a0 += fmaxf(hs.x + ea.x, 0.f);
    a1 += fmaxf(hs.y + ea.y, 0.f);
  }
  float2 hn = *reinterpret_cast<const float2*>(h + (size_t)n * HD + c2);
  ushort2 u = { f2bf(hn.x + a0), f2bf(hn.y + a1) };
  *reinterpret_cast<ushort2*>(z_bf + (size_t)n * HD + c2) = u;
}

// ---------------- sparse attention, wave-per-node over CSR-by-src, online softmax ----------------
// lane layout: head = lane>>3 (8 lanes/head), each lane owns dims {2j, 2j+1}, j = lane&7; col = 2*lane
// adj_src[i] = dst[eid] pre-resolved; 4-way unroll + pipelined adjacency prefetch.
__global__ __launch_bounds__(256) void attn_kernel(const ushort_t* __restrict__ qb, const ushort_t* __restrict__ kb,
                                                   const ushort_t* __restrict__ vb, const int* __restrict__ off_src,
                                                   const int* __restrict__ adj_src,
                                                   const float* __restrict__ h, float* __restrict__ X2, int N) {
  int wave = threadIdx.x >> 6, lane = threadIdx.x & 63;
  int n = blockIdx.x * 4 + wave;
  if (n >= N) return;
  int c2 = lane * 2;
  float2 qv = ldbf2(qb + (size_t)n * HD + c2);
  float m = -__builtin_inff(), l = 0.f, a0 = 0.f, a1 = 0.f;
  int beg = off_src[n], end = off_src[n + 1];
  int i = beg;
  int mainend = beg + ((end - beg) & ~3);
  if (i < mainend) {
    int d0 = adj_src[i], d1 = adj_src[i + 1], d2 = adj_src[i + 2], d3 = adj_src[i + 3];
    for (;;) {
      float2 k0 = ldbf2(kb + (size_t)d0 * HD + c2);
      float2 k1 = ldbf2(kb + (size_t)d1 * HD + c2);
      float2 k2 = ldbf2(kb + (size_t)d2 * HD + c2);
      float2 k3 = ldbf2(kb + (size_t)d3 * HD + c2);
      float2 v0 = ldbf2(vb + (size_t)d0 * HD + c2);
      float2 v1 = ldbf2(vb + (size_t)d1 * HD + c2);
      float2 v2 = ldbf2(vb + (size_t)d2 * HD + c2);
      float2 v3 = ldbf2(vb + (size_t)d3 * HD + c2);
      int ni = i + 4;
      int pi = (ni < mainend) ? ni : beg;
      int e0 = adj_src[pi], e1 = adj_src[pi + 1], e2 = adj_src[pi + 2], e3 = adj_src[pi + 3];
      float s0 = qv.x * k0.x + qv.y * k0.y;
      float s1 = qv.x * k1.x + qv.y * k1.y;
      float s2 = qv.x * k2.x + qv.y * k2.y;
      float s3 = qv.x * k3.x + qv.y * k3.y;
      s0 += __shfl_xor(s0, 1, 64); s0 += __shfl_xor(s0, 2, 64); s0 += __shfl_xor(s0, 4, 64);
      s1 += __shfl_xor(s1, 1, 64); s1 += __shfl_xor(s1, 2, 64); s1 += __shfl_xor(s1, 4, 64);
      s2 += __shfl_xor(s2, 1, 64); s2 += __shfl_xor(s2, 2, 64); s2 += __shfl_xor(s2, 4, 64);
      s3 += __shfl_xor(s3, 1, 64); s3 += __shfl_xor(s3, 2, 64); s3 += __shfl_xor(s3, 4, 64);
      float smax = fmaxf(fmaxf(s0, s1), fmaxf(s2, s3));
      float nm = fmaxf(m, smax);
      float al = __expf(m - nm);  // m=-inf first block -> 0
      float p0 = __expf(s0 - nm), p1 = __expf(s1 - nm), p2 = __expf(s2 - nm), p3 = __expf(s3 - nm);
      l = l * al + ((p0 + p1) + (p2 + p3));
      a0 = a0 * al + ((p0 * v0.x + p1 * v1.x) + (p2 * v2.x + p3 * v3.x));
      a1 = a1 * al + ((p0 * v0.y + p1 * v1.y) + (p2 * v2.y + p3 * v3.y));
      m = nm;
      d0 = e0; d1 = e1; d2 = e2; d3 = e3;
      i = ni;
      if (i >= mainend) break;
    }
  }
  for (; i < end; ++i) {
    int d = adj_src[i];
    float2 kd = ldbf2(kb + (size_t)d * HD + c2);
    float s = qv.x * kd.x + qv.y * kd.y;
    s += __shfl_xor(s, 1, 64);
    s += __shfl_xor(s, 2, 64);
    s += __shfl_xor(s, 4, 64);
    float2 vd = ldbf2(vb + (size_t)d * HD + c2);
    float nm = fmaxf(m, s);
    float al = __expf(m - nm);
    float p = __expf(s - nm);
    l = l * al + p;
    a0 = a0 * al + p * vd.x;
    a1 = a1 * al + p * vd.y;
    m = nm;
  }
  float inv = (end > beg) ? 1.0f / l : 0.f;
  size_t base = (size_t)n * HD + c2;
  float2 hv = *reinterpret_cast<const float2*>(h + base);
  float2 o = make_float2(hv.x + a0 * inv, hv.y + a1 * inv);
  *reinterpret_cast<float2*>(X2 + base) = o;
}

// ---------------- BN column stats ----------------
__global__ __launch_bounds__(256) void stats_kernel(const float* __restrict__ X, float* __restrict__ sums,
                                                    float* __restrict__ sumsq, int N) {
  int col = threadIdx.x & 127, half = threadIdx.x >> 7;
  float s = 0.f, s2 = 0.f;
  for (int r = blockIdx.x * 2 + half; r < N; r += gridDim.x * 2) {
    float v = X[(size_t)r * HD + col];
    s += v;
    s2 += v * v;
  }
  __shared__ float ls[256], ls2[256];
  ls[threadIdx.x] = s;
  ls2[threadIdx.x] = s2;
  __syncthreads();
  if (half == 0) {
    s += ls[threadIdx.x + 128];
    s2 += ls2[threadIdx.x + 128];
    atomicAdd(&sums[col], s);
    atomicAdd(&sumsq[col], s2);
  }
}

__global__ void coeff_kernel(const float* __restrict__ sums, const float* __restrict__ sumsq,
                             const float* __restrict__ g, const float* __restrict__ b, float* __restrict__ ab, int N) {
  int c = threadIdx.x;  // 128
  float inv_n = 1.0f / (float)N;
  float mu = sums[c] * inv_n;
  float var = sumsq[c] * inv_n - mu * mu;
  float a = g[c] * rsqrtf(var + 1e-5f);
  ab[c] = a;
  ab[128 + c] = b[c] - mu * a;
}

// hc = bn1(X1) + bn2(X2), write fp32 + bf16
__global__ __launch_bounds__(256) void combine_kernel(const float* __restrict__ X1, const float* __restrict__ X2,
                                                      const float* __restrict__ ab1, const float* __restrict__ ab2,
                                                      float* __restrict__ hc_f, ushort_t* __restrict__ hc_b, int total4) {
  int i = blockIdx.x * 256 + threadIdx.x;
  if (i >= total4) return;
  float4 x1 = reinterpret_cast<const float4*>(X1)[i];
  float4 x2 = reinterpret_cast<const float4*>(X2)[i];
  int c = (i * 4) & 127;
  float4 r;
  r.x = x1.x * ab1[c + 0] + ab1[128 + c + 0] + x2.x * ab2[c + 0] + ab2[128 + c + 0];
  r.y = x1.y * ab1[c + 1] + ab1[128 + c + 1] + x2.y * ab2[c + 1] + ab2[128 + c + 1];
  r.z = x1.z * ab1[c + 2] + ab1[128 + c + 2] + x2.z * ab2[c + 2] + ab2[128 + c + 2];
  r.w = x1.w * ab1[c + 3] + ab1[128 + c + 3] + x2.w * ab2[c + 3] + ab2[128 + c + 3];
  reinterpret_cast<float4*>(hc_f)[i] = r;
  ushort4 u = { f2bf(r.x), f2bf(r.y), f2bf(r.z), f2bf(r.w) };
  reinterpret_cast<ushort4*>(hc_b)[i] = u;
}

__global__ __launch_bounds__(256) void final_kernel(const float* __restrict__ X3, const float* __restrict__ ab,
                                                    float* __restrict__ out, int total4) {
  int i = blockIdx.x * 256 + threadIdx.x;
  if (i >= total4) return;
  float4 x = reinterpret_cast<const float4*>(X3)[i];
  int c = (i * 4) & 127;
  float4 r;
  r.x = x.x * ab[c + 0] + ab[128 + c + 0];
  r.y = x.y * ab[c + 1] + ab[128 + c + 1];
  r.z = x.z * ab[c + 2] + ab[128 + c + 2];
  r.w = x.w * ab[c + 3] + ab[128 + c + 3];
  reinterpret_cast<float4*>(out)[i] = r;
}

extern "C" void kernel_launch(void* const* d_in, const int* in_sizes, int n_in,
                              void* d_out, int out_size, void* d_ws, size_t ws_size,
                              hipStream_t stream) {
  const float* h = (const float*)d_in[0];
  const float* eattr = (const float*)d_in[1];
  const int* src = (const int*)d_in[2];
  const int* dst = (const int*)d_in[3];
  const float* gin_w1 = (const float*)d_in[4];
  const float* gin_b1 = (const float*)d_in[5];
  const float* gin_w2 = (const float*)d_in[6];
  const float* gin_b2 = (const float*)d_in[7];
  const float* wq = (const float*)d_in[8];
  const float* bq = (const float*)d_in[9];
  const float* wk = (const float*)d_in[10];
  const float* bk = (const float*)d_in[11];
  const float* wv = (const float*)d_in[12];
  const float* bv = (const float*)d_in[13];
  const float* nl_g = (const float*)d_in[14];
  const float* nl_b = (const float*)d_in[15];
  const float* na_g = (const float*)d_in[16];
  const float* na_b = (const float*)d_in[17];
  const float* no_g = (const float*)d_in[18];
  const float* no_b = (const float*)d_in[19];
  const float* ffn1_w = (const float*)d_in[20];
  const float* ffn1_b = (const float*)d_in[21];
  const float* ffn2_w = (const float*)d_in[22];
  const float* ffn2_b = (const float*)d_in[23];

  const int N = NN, E = NE;
  char* ws = (char*)d_ws;
  size_t off = 0;
  auto alloc = [&](size_t bytes) -> void* {
    void* p = ws + off;
    off += (bytes + 255) & ~(size_t)255;
    return p;
  };

  ushort_t* h_bf = (ushort_t*)alloc((size_t)N * HD * 2);
  ushort_t* q_bf = (ushort_t*)alloc((size_t)N * HD * 2);
  ushort_t* k_bf = (ushort_t*)alloc((size_t)N * HD * 2);
  ushort_t* v_bf = (ushort_t*)alloc((size_t)N * HD * 2);
  ushort_t* z_bf = (ushort_t*)alloc((size_t)N * HD * 2);
  ushort_t* mid1 = (ushort_t*)alloc((size_t)N * HD * 2);
  ushort_t* hc_bf = (ushort_t*)alloc((size_t)N * HD * 2);
  ushort_t* mid2 = (ushort_t*)alloc((size_t)N * 256 * 2);
  float* X1 = (float*)alloc((size_t)N * HD * 4);
  float* X2 = (float*)alloc((size_t)N * HD * 4);
  float* X3 = (float*)alloc((size_t)N * HD * 4);
  float* hc_f = (float*)alloc((size_t)N * HD * 4);
  // ---- zero-init region (one memset) ----
  int* deg_dst = (int*)alloc((size_t)N * 4);
  int* deg_src = (int*)alloc((size_t)N * 4);
  float* stats = (float*)alloc(6 * 128 * 4);  // sums1,sq1,sums2,sq2,sums3,sq3
  size_t zero_bytes = (size_t)((char*)(stats + 6 * 128) - (char*)deg_dst);
  // ---- end zero region ----
  int* off_dst = (int*)alloc((size_t)(N + 1) * 4);
  int* off_src = (int*)alloc((size_t)(N + 1) * 4);
  int* cur_dst = (int*)alloc((size_t)N * 4);
  int* cur_src = (int*)alloc((size_t)N * 4);
  int2* pair_dst = (int2*)alloc((size_t)E * 8);
  int* adj_src = (int*)alloc((size_t)E * 4);
  float* ab1 = (float*)alloc(256 * 4);
  float* ab2 = (float*)alloc(256 * 4);
  float* ab3 = (float*)alloc(256 * 4);

  float* sums1 = stats, *sq1 = stats + 128;
  float* sums2 = stats + 256, *sq2 = stats + 384;
  float* sums3 = stats + 512, *sq3 = stats + 640;

  float* out_hc = (float*)d_out;
  float* out_eattr = (float*)d_out + (size_t)N * HD;

  hipMemsetAsync(deg_dst, 0, zero_bytes, stream);

  const int egrid = (E + 255) / 256;
  hist_kernel<<<egrid, 256, 0, stream>>>(src, dst, deg_src, deg_dst, E);
  scan_kernel<<<2, 1024, 0, stream>>>(deg_dst, deg_src, off_dst, cur_dst, off_src, cur_src, N);
  scatter_kernel<<<egrid, 256, 0, stream>>>(src, dst, cur_src, cur_dst, adj_src, pair_dst, E);

  const int total4 = N * HD / 4;
  const int cgrid = (total4 + 255) / 256;
  hconv_kernel<<<cgrid, 256, 0, stream>>>(h, h_bf, total4);

  const int ggrid = (N / 16 + 3) / 4;
  const float scale = 0.25f;  // DH^-0.5
  gemm_kernel<128, 128, 4><<<ggrid, 256, 0, stream>>>(h_bf, wq, bq, nullptr, q_bf, scale, N);
  gemm_kernel<128, 128, 4><<<ggrid, 256, 0, stream>>>(h_bf, wk, bk, nullptr, k_bf, 1.0f, N);
  gemm_kernel<128, 128, 4><<<ggrid, 256, 0, stream>>>(h_bf, wv, bv, nullptr, v_bf, 1.0f, N);

  agg_kernel<<<N / 4, 256, 0, stream>>>(h, eattr, off_dst, pair_dst, out_eattr, z_bf, N);
  gemm_kernel<128, 128, 5><<<ggrid, 256, 0, stream>>>(z_bf, gin_w1, gin_b1, nullptr, mid1, 1.0f, N);  // relu, bf16
  gemm_kernel<128, 128, 2><<<ggrid, 256, 0, stream>>>(mid1, gin_w2, gin_b2, h, X1, 1.0f, N);          // +h, fp32

  attn_kernel<<<N / 4, 256, 0, stream>>>(q_bf, k_bf, v_bf, off_src, adj_src, h, X2, N);

  stats_kernel<<<256, 256, 0, stream>>>(X1, sums1, sq1, N);
  stats_kernel<<<256, 256, 0, stream>>>(X2, sums2, sq2, N);
  coeff_kernel<<<1, 128, 0, stream>>>(sums1, sq1, nl_g, nl_b, ab1, N);
  coeff_kernel<<<1, 128, 0, stream>>>(sums2, sq2, na_g, na_b, ab2, N);
  combine_kernel<<<cgrid, 256, 0, stream>>>(X1, X2, ab1, ab2, hc_f, hc_bf, total4);

  gemm_kernel<128, 256, 5><<<ggrid, 256, 0, stream>>>(hc_bf, ffn1_w, ffn1_b, nullptr, mid2, 1.0f, N);  // relu, bf16
  gemm_kernel<256, 128, 2><<<ggrid, 256, 0, stream>>>(mid2, ffn2_w, ffn2_b, hc_f, X3, 1.0f, N);        // +hc, fp32

  stats_kernel<<<256, 256, 0, stream>>>(X3, sums3, sq3, N);
  coeff_kernel<<<1, 128, 0, stream>>>(sums3, sq3, no_g, no_b, ab3, N);
  final_kernel<<<cgrid, 256, 0, stream>>>(X3, ab3, out_hc, total4);
}

// Round 3
// 961.529 us; speedup vs baseline: 1.1760x; 1.0433x over previous
//
#include <hip/hip_runtime.h>

#define NN 50000
#define NE 500000
#define HD 128

typedef unsigned short ushort_t;
typedef __bf16 bf16x8 __attribute__((ext_vector_type(8)));
typedef float f32x4 __attribute__((ext_vector_type(4)));
typedef float f32x2 __attribute__((ext_vector_type(2)));  // clang-native vector: valid for nontemporal builtins

static __device__ __forceinline__ unsigned short f2bf(float f) {
  unsigned int u = __float_as_uint(f);
  unsigned int r = (u + 0x7fffu + ((u >> 16) & 1u)) >> 16;  // RNE
  return (unsigned short)r;
}
static __device__ __forceinline__ float2 ldbf2(const unsigned short* p) {
  unsigned int u = *reinterpret_cast<const unsigned int*>(p);
  return make_float2(__uint_as_float(u << 16), __uint_as_float(u & 0xffff0000u));
}

// ---------------- CSR build ----------------
__global__ __launch_bounds__(256) void hist_kernel(const int* __restrict__ src, const int* __restrict__ dst,
                                                   int* __restrict__ deg_src, int* __restrict__ deg_dst, int E) {
  int e = blockIdx.x * 256 + threadIdx.x;
  if (e < E) {
    atomicAdd(&deg_dst[dst[e]], 1);
    atomicAdd(&deg_src[src[e]], 1);
  }
}

__global__ __launch_bounds__(1024) void scan_kernel(const int* __restrict__ deg_dst, const int* __restrict__ deg_src,
                                                    int* __restrict__ off_dst, int* __restrict__ cur_dst,
                                                    int* __restrict__ off_src, int* __restrict__ cur_src, int N) {
  const int* deg = blockIdx.x ? deg_src : deg_dst;
  int* off = blockIdx.x ? off_src : off_dst;
  int* cur = blockIdx.x ? cur_src : cur_dst;
  const int CH = (N + 1023) / 1024;
  int t = threadIdx.x;
  int base = t * CH;
  int sum = 0;
  for (int i = 0; i < CH; ++i) { int idx = base + i; if (idx < N) sum += deg[idx]; }
  __shared__ int ls[1024];
  ls[t] = sum;
  __syncthreads();
  for (int o = 1; o < 1024; o <<= 1) {
    int u = (t >= o) ? ls[t - o] : 0;
    __syncthreads();
    ls[t] += u;
    __syncthreads();
  }
  int run = ls[t] - sum;  // exclusive prefix of this thread's chunk
  for (int i = 0; i < CH; ++i) {
    int idx = base + i;
    if (idx < N) { off[idx] = run; cur[idx] = run; run += deg[idx]; }
  }
  if (t == 1023) off[N] = ls[1023];
}

// Pre-resolve adjacency: agg needs (e, src[e]) per CSR-by-dst slot; attn needs only dst[e] per CSR-by-src slot.
__global__ __launch_bounds__(256) void scatter_kernel(const int* __restrict__ src, const int* __restrict__ dst,
                                                      int* __restrict__ cur_src, int* __restrict__ cur_dst,
                                                      int* __restrict__ adj_src, int2* __restrict__ pair_dst, int E) {
  int e = blockIdx.x * 256 + threadIdx.x;
  if (e < E) {
    int s = src[e], d = dst[e];
    int p = atomicAdd(&cur_dst[d], 1); pair_dst[p] = make_int2(e, s);
    int q = atomicAdd(&cur_src[s], 1); adj_src[q] = d;
  }
}

// ---------------- generic small-K MFMA GEMM v2: out = epi(A @ W^T + bias) ----------------
// 2 row-tiles per wave (32 rows/wave, 128 rows/block): W staging amortized 2x vs v1.
// MODE bits: 1=relu, 2=add resid (fp32 [nrows,OUTC]), 4=bf16 out (else fp32),
//            8=fused BN column stats (atomicAdd into stats[0..OUTC-1]=sum, [OUTC..2*OUTC-1]=sumsq),
//            16=A is fp32 (convert to bf16 in-register; else A is bf16)
template <int K, int OUTC, int MODE>
__global__ __launch_bounds__(256) void gemm_kernel(const void* __restrict__ Ap, const float* __restrict__ W,
                                                   const float* __restrict__ bias, const float* __restrict__ resid,
                                                   void* __restrict__ out, float* __restrict__ stats,
                                                   float scale, int nrows) {
  constexpr int KP = K + 8;  // +16B pad per row: breaks LDS bank conflicts
  __shared__ __align__(16) ushort_t wlds[OUTC * KP];
  constexpr int NLOAD = OUTC * K / 4;
  for (int idx = threadIdx.x; idx < NLOAD; idx += 256) {
    int r = idx / (K / 4), c4 = idx % (K / 4);
    float4 wv = reinterpret_cast<const float4*>(W)[idx];
    ushort_t* d = &wlds[r * KP + c4 * 4];
    d[0] = f2bf(wv.x); d[1] = f2bf(wv.y); d[2] = f2bf(wv.z); d[3] = f2bf(wv.w);
  }
  __syncthreads();
  const int wave = threadIdx.x >> 6, lane = threadIdx.x & 63;
  const int m = lane & 15, quad = lane >> 4;
  const int row0 = (blockIdx.x * 4 + wave) * 32;
  // 16 | nrows, so each 16-row tile is fully in or fully out; no early return (stats barrier below).
  const bool vt[2] = { row0 < nrows, row0 + 16 < nrows };
  bf16x8 afrag[2][K / 32];
#pragma unroll
  for (int t = 0; t < 2; ++t) {
    int rowt = vt[t] ? (row0 + t * 16 + m) : 0;  // safe dummy row when OOB
    if constexpr (MODE & 16) {
      const float* ar = (const float*)Ap + (size_t)rowt * K + quad * 8;
#pragma unroll
      for (int kk = 0; kk < K / 32; ++kk) {
        float4 x = *reinterpret_cast<const float4*>(ar + kk * 32);
        float4 y = *reinterpret_cast<const float4*>(ar + kk * 32 + 4);
        union { bf16x8 v8; ushort_t u[8]; } pk;
        pk.u[0] = f2bf(x.x); pk.u[1] = f2bf(x.y); pk.u[2] = f2bf(x.z); pk.u[3] = f2bf(x.w);
        pk.u[4] = f2bf(y.x); pk.u[5] = f2bf(y.y); pk.u[6] = f2bf(y.z); pk.u[7] = f2bf(y.w);
        afrag[t][kk] = pk.v8;
      }
    } else {
      const ushort_t* ar = (const ushort_t*)Ap + (size_t)rowt * K + quad * 8;
#pragma unroll
      for (int kk = 0; kk < K / 32; ++kk)
        afrag[t][kk] = *reinterpret_cast<const bf16x8*>(ar + kk * 32);
    }
  }
  f32x4 acc[2][OUTC / 16] = {};
#pragma unroll
  for (int c = 0; c < OUTC / 16; ++c) {
    const ushort_t* wr = &wlds[(c * 16 + m) * KP + quad * 8];
#pragma unroll
    for (int kk = 0; kk < K / 32; ++kk) {
      bf16x8 bfrag = *reinterpret_cast<const bf16x8*>(wr + kk * 32);
      acc[0][c] = __builtin_amdgcn_mfma_f32_16x16x32_bf16(afrag[0][kk], bfrag, acc[0][c], 0, 0, 0);
      acc[1][c] = __builtin_amdgcn_mfma_f32_16x16x32_bf16(afrag[1][kk], bfrag, acc[1][c], 0, 0, 0);
    }
  }
  float s1r[OUTC / 16] = {}, s2r[OUTC / 16] = {};
#pragma unroll
  for (int t = 0; t < 2; ++t) {
    if (vt[t]) {  // wave-uniform
#pragma unroll
      for (int c = 0; c < OUTC / 16; ++c) {
        int col = c * 16 + m;
        float bv = bias[col];
#pragma unroll
        for (int r = 0; r < 4; ++r) {
          int grow = row0 + t * 16 + quad * 4 + r;  // C/D layout: row=(lane>>4)*4+reg, col=lane&15
          float val = (acc[t][c][r] + bv) * scale;
          if constexpr (MODE & 1) val = fmaxf(val, 0.0f);
          if constexpr (MODE & 2) val += resid[(size_t)grow * OUTC + col];
          if constexpr (MODE & 4) ((ushort_t*)out)[(size_t)grow * OUTC + col] = f2bf(val);
          else ((float*)out)[(size_t)grow * OUTC + col] = val;
          if constexpr (MODE & 8) { s1r[c] += val; s2r[c] += val * val; }
        }
      }
    }
  }
  if constexpr (MODE & 8) {
    // reduce over quads (lanes m, m+16, m+32, m+48 share col set)
#pragma unroll
    for (int c = 0; c < OUTC / 16; ++c) {
      s1r[c] += __shfl_xor(s1r[c], 16, 64); s1r[c] += __shfl_xor(s1r[c], 32, 64);
      s2r[c] += __shfl_xor(s2r[c], 16, 64); s2r[c] += __shfl_xor(s2r[c], 32, 64);
    }
    __shared__ float sred[2][4][OUTC / 16][16];
    if (lane < 16) {
#pragma unroll
      for (int c = 0; c < OUTC / 16; ++c) {
        sred[0][wave][c][lane] = s1r[c];
        sred[1][wave][c][lane] = s2r[c];
      }
    }
    __syncthreads();
    int tid = threadIdx.x;
    if (tid < 2 * OUTC) {
      int which = tid >= OUTC ? 1 : 0;
      int col = tid - which * OUTC;
      float tot = sred[which][0][col >> 4][col & 15] + sred[which][1][col >> 4][col & 15] +
                  sred[which][2][col >> 4][col & 15] + sred[which][3][col >> 4][col & 15];
      atomicAdd(&stats[which * OUTC + col], tot);
    }
  }
}

// ---------------- fused Q/K/V projection: reads h fp32 once, A-fragments reused for 3 matmuls ----------------
__global__ __launch_bounds__(256) void qkv_kernel(const float* __restrict__ h,
                                                  const float* __restrict__ wq, const float* __restrict__ bq,
                                                  const float* __restrict__ wk, const float* __restrict__ bk,
                                                  const float* __restrict__ wv, const float* __restrict__ bv,
                                                  ushort_t* __restrict__ qb, ushort_t* __restrict__ kb,
                                                  ushort_t* __restrict__ vb, int nrows) {
  constexpr int K = HD, OUTC = HD, KP = K + 8;
  __shared__ __align__(16) ushort_t wlds[OUTC * KP];
  const int wave = threadIdx.x >> 6, lane = threadIdx.x & 63;
  const int m = lane & 15, quad = lane >> 4;
  const int row0 = (blockIdx.x * 4 + wave) * 32;
  const bool vt[2] = { row0 < nrows, row0 + 16 < nrows };
  bf16x8 afrag[2][K / 32];
#pragma unroll
  for (int t = 0; t < 2; ++t) {
    int rowt = vt[t] ? (row0 + t * 16 + m) : 0;
    const float* ar = h + (size_t)rowt * K + quad * 8;
#pragma unroll
    for (int kk = 0; kk < K / 32; ++kk) {
      float4 x = *reinterpret_cast<const float4*>(ar + kk * 32);
      float4 y = *reinterpret_cast<const float4*>(ar + kk * 32 + 4);
      union { bf16x8 v8; ushort_t u[8]; } pk;
      pk.u[0] = f2bf(x.x); pk.u[1] = f2bf(x.y); pk.u[2] = f2bf(x.z); pk.u[3] = f2bf(x.w);
      pk.u[4] = f2bf(y.x); pk.u[5] = f2bf(y.y); pk.u[6] = f2bf(y.z); pk.u[7] = f2bf(y.w);
      afrag[t][kk] = pk.v8;
    }
  }
  const float* Ws[3] = { wq, wk, wv };
  const float* Bs[3] = { bq, bk, bv };
  ushort_t* Os[3] = { qb, kb, vb };
  for (int w = 0; w < 3; ++w) {
    const float* W = Ws[w];
    constexpr int NLOAD = OUTC * K / 4;
    for (int idx = threadIdx.x; idx < NLOAD; idx += 256) {
      int r = idx / (K / 4), c4 = idx % (K / 4);
      float4 wv4 = reinterpret_cast<const float4*>(W)[idx];
      ushort_t* d = &wlds[r * KP + c4 * 4];
      d[0] = f2bf(wv4.x); d[1] = f2bf(wv4.y); d[2] = f2bf(wv4.z); d[3] = f2bf(wv4.w);
    }
    __syncthreads();
    f32x4 acc[2][OUTC / 16] = {};
#pragma unroll
    for (int c = 0; c < OUTC / 16; ++c) {
      const ushort_t* wr = &wlds[(c * 16 + m) * KP + quad * 8];
#pragma unroll
      for (int kk = 0; kk < K / 32; ++kk) {
        bf16x8 bfrag = *reinterpret_cast<const bf16x8*>(wr + kk * 32);
        acc[0][c] = __builtin_amdgcn_mfma_f32_16x16x32_bf16(afrag[0][kk], bfrag, acc[0][c], 0, 0, 0);
        acc[1][c] = __builtin_amdgcn_mfma_f32_16x16x32_bf16(afrag[1][kk], bfrag, acc[1][c], 0, 0, 0);
      }
    }
    float scl = (w == 0) ? 0.25f : 1.0f;  // DH^-0.5 folded into q
    ushort_t* O = Os[w];
    const float* B = Bs[w];
#pragma unroll
    for (int t = 0; t < 2; ++t) {
      if (vt[t]) {
#pragma unroll
        for (int c = 0; c < OUTC / 16; ++c) {
          int col = c * 16 + m;
          float bv = B[col];
#pragma unroll
          for (int r = 0; r < 4; ++r) {
            int grow = row0 + t * 16 + quad * 4 + r;
            O[(size_t)grow * OUTC + col] = f2bf((acc[t][c][r] + bv) * scl);
          }
        }
      }
    }
    __syncthreads();  // all waves done reading wlds before next stage overwrites
  }
}

// ---------------- GINE aggregation + eattr passthrough copy ----------------
// wave-per-node over CSR-by-dst: z = h[n] + sum_e relu(h[src[e]] + eattr[e]); also out_eattr[e] = eattr[e]
// Latency-bound loop: 4-way unroll + software-pipelined pair prefetch -> >=8 loads in flight per wave.
__global__ __launch_bounds__(256) void agg_kernel(const float* __restrict__ h, const float* __restrict__ eattr,
                                                  const int* __restrict__ off_dst, const int2* __restrict__ pair_dst,
                                                  float* __restrict__ out_eattr, ushort_t* __restrict__ z_bf, int N) {
  int wave = threadIdx.x >> 6, lane = threadIdx.x & 63;
  int n = blockIdx.x * 4 + wave;
  if (n >= N) return;
  int c2 = lane * 2;
  float a0 = 0.f, a1 = 0.f;
  int beg = off_dst[n], end = off_dst[n + 1];
  int i = beg;
  int mainend = beg + ((end - beg) & ~3);
  if (i < mainend) {
    int2 p0 = pair_dst[i], p1 = pair_dst[i + 1], p2 = pair_dst[i + 2], p3 = pair_dst[i + 3];
    for (;;) {
      f32x2 ea0 = __builtin_nontemporal_load(reinterpret_cast<const f32x2*>(eattr + (size_t)p0.x * HD + c2));
      f32x2 ea1 = __builtin_nontemporal_load(reinterpret_cast<const f32x2*>(eattr + (size_t)p1.x * HD + c2));
      f32x2 ea2 = __builtin_nontemporal_load(reinterpret_cast<const f32x2*>(eattr + (size_t)p2.x * HD + c2));
      f32x2 ea3 = __builtin_nontemporal_load(reinterpret_cast<const f32x2*>(eattr + (size_t)p3.x * HD + c2));
      f32x2 hs0 = *reinterpret_cast<const f32x2*>(h + (size_t)p0.y * HD + c2);
      f32x2 hs1 = *reinterpret_cast<const f32x2*>(h + (size_t)p1.y * HD + c2);
      f32x2 hs2 = *reinterpret_cast<const f32x2*>(h + (size_t)p2.y * HD + c2);
      f32x2 hs3 = *reinterpret_cast<const f32x2*>(h + (size_t)p3.y * HD + c2);
      int ni = i + 4;
      int pi = (ni < mainend) ? ni : beg;  // safe prefetch address (nmain>=4 guaranteed)
      int2 q0 = pair_dst[pi], q1 = pair_dst[pi + 1], q2 = pair_dst[pi + 2], q3 = pair_dst[pi + 3];
      __builtin_nontemporal_store(ea0, reinterpret_cast<f32x2*>(out_eattr + (size_t)p0.x * HD + c2));
      __builtin_nontemporal_store(ea1, reinterpret_cast<f32x2*>(out_eattr + (size_t)p1.x * HD + c2));
      __builtin_nontemporal_store(ea2, reinterpret_cast<f32x2*>(out_eattr + (size_t)p2.x * HD + c2));
      __builtin_nontemporal_store(ea3, reinterpret_cast<f32x2*>(out_eattr + (size_t)p3.x * HD + c2));
      a0 += (fmaxf(hs0.x + ea0.x, 0.f) + fmaxf(hs1.x + ea1.x, 0.f)) +
            (fmaxf(hs2.x + ea2.x, 0.f) + fmaxf(hs3.x + ea3.x, 0.f));
      a1 += (fmaxf(hs0.y + ea0.y, 0.f) + fmaxf(hs1.y + ea1.y, 0.f)) +
            (fmaxf(hs2.y + ea2.y, 0.f) + fmaxf(hs3.y + ea3.y, 0.f));
      p0 = q0; p1 = q1; p2 = q2; p3 = q3;
      i = ni;
      if (i >= mainend) break;
    }
  }
  for (; i < end; ++i) {
    int2 p = pair_dst[i];
    f32x2 ea = __builtin_nontemporal_load(reinterpret_cast<const f32x2*>(eattr + (size_t)p.x * HD + c2));
    f32x2 hs = *reinterpret_cast<const f32x2*>(h + (size_t)p.y * HD + c2);
    __builtin_nontemporal_store(ea, reinterpret_cast<f32x2*>(out_eattr + (size_t)p.x * HD + c2));
    a0 += fmaxf(hs.x + ea.x, 0.f);
    a1 += fmaxf(hs.y + ea.y, 0.f);
  }
  float2 hn = *reinterpret_cast<const float2*>(h + (size_t)n * HD + c2);
  ushort2 u = { f2bf(hn.x + a0), f2bf(hn.y + a1) };
  *reinterpret_cast<ushort2*>(z_bf + (size_t)n * HD + c2) = u;
}

// ---------------- sparse attention, wave-per-node over CSR-by-src, online softmax ----------------
// lane layout: head = lane>>3 (8 lanes/head), each lane owns dims {2j, 2j+1}, j = lane&7; col = 2*lane
// adj_src[i] = dst[eid] pre-resolved; 4-way unroll + pipelined adjacency prefetch.
__global__ __launch_bounds__(256) void attn_kernel(const ushort_t* __restrict__ qb, const ushort_t* __restrict__ kb,
                                                   const ushort_t* __restrict__ vb, const int* __restrict__ off_src,
                                                   const int* __restrict__ adj_src,
                                                   const float* __restrict__ h, float* __restrict__ X2, int N) {
  int wave = threadIdx.x >> 6, lane = threadIdx.x & 63;
  int n = blockIdx.x * 4 + wave;
  if (n >= N) return;
  int c2 = lane * 2;
  float2 qv = ldbf2(qb + (size_t)n * HD + c2);
  float m = -__builtin_inff(), l = 0.f, a0 = 0.f, a1 = 0.f;
  int beg = off_src[n], end = off_src[n + 1];
  int i = beg;
  int mainend = beg + ((end - beg) & ~3);
  if (i < mainend) {
    int d0 = adj_src[i], d1 = adj_src[i + 1], d2 = adj_src[i + 2], d3 = adj_src[i + 3];
    for (;;) {
      float2 k0 = ldbf2(kb + (size_t)d0 * HD + c2);
      float2 k1 = ldbf2(kb + (size_t)d1 * HD + c2);
      float2 k2 = ldbf2(kb + (size_t)d2 * HD + c2);
      float2 k3 = ldbf2(kb + (size_t)d3 * HD + c2);
      float2 v0 = ldbf2(vb + (size_t)d0 * HD + c2);
      float2 v1 = ldbf2(vb + (size_t)d1 * HD + c2);
      float2 v2 = ldbf2(vb + (size_t)d2 * HD + c2);
      float2 v3 = ldbf2(vb + (size_t)d3 * HD + c2);
      int ni = i + 4;
      int pi = (ni < mainend) ? ni : beg;
      int e0 = adj_src[pi], e1 = adj_src[pi + 1], e2 = adj_src[pi + 2], e3 = adj_src[pi + 3];
      float s0 = qv.x * k0.x + qv.y * k0.y;
      float s1 = qv.x * k1.x + qv.y * k1.y;
      float s2 = qv.x * k2.x + qv.y * k2.y;
      float s3 = qv.x * k3.x + qv.y * k3.y;
      s0 += __shfl_xor(s0, 1, 64); s0 += __shfl_xor(s0, 2, 64); s0 += __shfl_xor(s0, 4, 64);
      s1 += __shfl_xor(s1, 1, 64); s1 += __shfl_xor(s1, 2, 64); s1 += __shfl_xor(s1, 4, 64);
      s2 += __shfl_xor(s2, 1, 64); s2 += __shfl_xor(s2, 2, 64); s2 += __shfl_xor(s2, 4, 64);
      s3 += __shfl_xor(s3, 1, 64); s3 += __shfl_xor(s3, 2, 64); s3 += __shfl_xor(s3, 4, 64);
      float smax = fmaxf(fmaxf(s0, s1), fmaxf(s2, s3));
      float nm = fmaxf(m, smax);
      float al = __expf(m - nm);  // m=-inf first block -> 0
      float p0 = __expf(s0 - nm), p1 = __expf(s1 - nm), p2 = __expf(s2 - nm), p3 = __expf(s3 - nm);
      l = l * al + ((p0 + p1) + (p2 + p3));
      a0 = a0 * al + ((p0 * v0.x + p1 * v1.x) + (p2 * v2.x + p3 * v3.x));
      a1 = a1 * al + ((p0 * v0.y + p1 * v1.y) + (p2 * v2.y + p3 * v3.y));
      m = nm;
      d0 = e0; d1 = e1; d2 = e2; d3 = e3;
      i = ni;
      if (i >= mainend) break;
    }
  }
  for (; i < end; ++i) {
    int d = adj_src[i];
    float2 kd = ldbf2(kb + (size_t)d * HD + c2);
    float s = qv.x * kd.x + qv.y * kd.y;
    s += __shfl_xor(s, 1, 64);
    s += __shfl_xor(s, 2, 64);
    s += __shfl_xor(s, 4, 64);
    float2 vd = ldbf2(vb + (size_t)d * HD + c2);
    float nm = fmaxf(m, s);
    float al = __expf(m - nm);
    float p = __expf(s - nm);
    l = l * al + p;
    a0 = a0 * al + p * vd.x;
    a1 = a1 * al + p * vd.y;
    m = nm;
  }
  float inv = (end > beg) ? 1.0f / l : 0.f;
  size_t base = (size_t)n * HD + c2;
  float2 hv = *reinterpret_cast<const float2*>(h + base);
  float2 o = make_float2(hv.x + a0 * inv, hv.y + a1 * inv);
  *reinterpret_cast<float2*>(X2 + base) = o;
}

// ---------------- BN column stats (only needed for X2; X1/X3 stats fused into GEMM epilogues) ----------------
__global__ __launch_bounds__(256) void stats_kernel(const float* __restrict__ X, float* __restrict__ sums,
                                                    float* __restrict__ sumsq, int N) {
  int col = threadIdx.x & 127, half = threadIdx.x >> 7;
  float s = 0.f, s2 = 0.f;
  for (int r = blockIdx.x * 2 + half; r < N; r += gridDim.x * 2) {
    float v = X[(size_t)r * HD + col];
    s += v;
    s2 += v * v;
  }
  __shared__ float ls[256], ls2[256];
  ls[threadIdx.x] = s;
  ls2[threadIdx.x] = s2;
  __syncthreads();
  if (half == 0) {
    s += ls[threadIdx.x + 128];
    s2 += ls2[threadIdx.x + 128];
    atomicAdd(&sums[col], s);
    atomicAdd(&sumsq[col], s2);
  }
}

__global__ void coeff_kernel(const float* __restrict__ sums, const float* __restrict__ sumsq,
                             const float* __restrict__ g, const float* __restrict__ b, float* __restrict__ ab, int N) {
  int c = threadIdx.x;  // 128
  float inv_n = 1.0f / (float)N;
  float mu = sums[c] * inv_n;
  float var = sumsq[c] * inv_n - mu * mu;
  float a = g[c] * rsqrtf(var + 1e-5f);
  ab[c] = a;
  ab[128 + c] = b[c] - mu * a;
}

// hc = bn1(X1) + bn2(X2), write fp32 only (ffn1 converts in-register)
__global__ __launch_bounds__(256) void combine_kernel(const float* __restrict__ X1, const float* __restrict__ X2,
                                                      const float* __restrict__ ab1, const float* __restrict__ ab2,
                                                      float* __restrict__ hc_f, int total4) {
  int i = blockIdx.x * 256 + threadIdx.x;
  if (i >= total4) return;
  float4 x1 = reinterpret_cast<const float4*>(X1)[i];
  float4 x2 = reinterpret_cast<const float4*>(X2)[i];
  int c = (i * 4) & 127;
  float4 r;
  r.x = x1.x * ab1[c + 0] + ab1[128 + c + 0] + x2.x * ab2[c + 0] + ab2[128 + c + 0];
  r.y = x1.y * ab1[c + 1] + ab1[128 + c + 1] + x2.y * ab2[c + 1] + ab2[128 + c + 1];
  r.z = x1.z * ab1[c + 2] + ab1[128 + c + 2] + x2.z * ab2[c + 2] + ab2[128 + c + 2];
  r.w = x1.w * ab1[c + 3] + ab1[128 + c + 3] + x2.w * ab2[c + 3] + ab2[128 + c + 3];
  reinterpret_cast<float4*>(hc_f)[i] = r;
}

__global__ __launch_bounds__(256) void final_kernel(const float* __restrict__ X3, const float* __restrict__ ab,
                                                    float* __restrict__ out, int total4) {
  int i = blockIdx.x * 256 + threadIdx.x;
  if (i >= total4) return;
  float4 x = reinterpret_cast<const float4*>(X3)[i];
  int c = (i * 4) & 127;
  float4 r;
  r.x = x.x * ab[c + 0] + ab[128 + c + 0];
  r.y = x.y * ab[c + 1] + ab[128 + c + 1];
  r.z = x.z * ab[c + 2] + ab[128 + c + 2];
  r.w = x.w * ab[c + 3] + ab[128 + c + 3];
  reinterpret_cast<float4*>(out)[i] = r;
}

extern "C" void kernel_launch(void* const* d_in, const int* in_sizes, int n_in,
                              void* d_out, int out_size, void* d_ws, size_t ws_size,
                              hipStream_t stream) {
  const float* h = (const float*)d_in[0];
  const float* eattr = (const float*)d_in[1];
  const int* src = (const int*)d_in[2];
  const int* dst = (const int*)d_in[3];
  const float* gin_w1 = (const float*)d_in[4];
  const float* gin_b1 = (const float*)d_in[5];
  const float* gin_w2 = (const float*)d_in[6];
  const float* gin_b2 = (const float*)d_in[7];
  const float* wq = (const float*)d_in[8];
  const float* bq = (const float*)d_in[9];
  const float* wk = (const float*)d_in[10];
  const float* bk = (const float*)d_in[11];
  const float* wv = (const float*)d_in[12];
  const float* bv = (const float*)d_in[13];
  const float* nl_g = (const float*)d_in[14];
  const float* nl_b = (const float*)d_in[15];
  const float* na_g = (const float*)d_in[16];
  const float* na_b = (const float*)d_in[17];
  const float* no_g = (const float*)d_in[18];
  const float* no_b = (const float*)d_in[19];
  const float* ffn1_w = (const float*)d_in[20];
  const float* ffn1_b = (const float*)d_in[21];
  const float* ffn2_w = (const float*)d_in[22];
  const float* ffn2_b = (const float*)d_in[23];

  const int N = NN, E = NE;
  char* ws = (char*)d_ws;
  size_t off = 0;
  auto alloc = [&](size_t bytes) -> void* {
    void* p = ws + off;
    off += (bytes + 255) & ~(size_t)255;
    return p;
  };

  ushort_t* q_bf = (ushort_t*)alloc((size_t)N * HD * 2);
  ushort_t* k_bf = (ushort_t*)alloc((size_t)N * HD * 2);
  ushort_t* v_bf = (ushort_t*)alloc((size_t)N * HD * 2);
  ushort_t* z_bf = (ushort_t*)alloc((size_t)N * HD * 2);
  ushort_t* mid1 = (ushort_t*)alloc((size_t)N * HD * 2);
  ushort_t* mid2 = (ushort_t*)alloc((size_t)N * 256 * 2);
  float* X1 = (float*)alloc((size_t)N * HD * 4);
  float* X2 = (float*)alloc((size_t)N * HD * 4);
  float* X3 = (float*)alloc((size_t)N * HD * 4);
  float* hc_f = (float*)alloc((size_t)N * HD * 4);
  // ---- zero-init region (one memset) ----
  int* deg_dst = (int*)alloc((size_t)N * 4);
  int* deg_src = (int*)alloc((size_t)N * 4);
  float* stats = (float*)alloc(6 * 128 * 4);  // sums1,sq1,sums2,sq2,sums3,sq3
  size_t zero_bytes = (size_t)((char*)(stats + 6 * 128) - (char*)deg_dst);
  // ---- end zero region ----
  int* off_dst = (int*)alloc((size_t)(N + 1) * 4);
  int* off_src = (int*)alloc((size_t)(N + 1) * 4);
  int* cur_dst = (int*)alloc((size_t)N * 4);
  int* cur_src = (int*)alloc((size_t)N * 4);
  int2* pair_dst = (int2*)alloc((size_t)E * 8);
  int* adj_src = (int*)alloc((size_t)E * 4);
  float* ab1 = (float*)alloc(256 * 4);
  float* ab2 = (float*)alloc(256 * 4);
  float* ab3 = (float*)alloc(256 * 4);

  float* sums1 = stats;
  float* sums2 = stats + 256;
  float* sums3 = stats + 512;
  float* sq2 = stats + 384;

  float* out_hc = (float*)d_out;
  float* out_eattr = (float*)d_out + (size_t)N * HD;

  hipMemsetAsync(deg_dst, 0, zero_bytes, stream);

  const int egrid = (E + 255) / 256;
  hist_kernel<<<egrid, 256, 0, stream>>>(src, dst, deg_src, deg_dst, E);
  scan_kernel<<<2, 1024, 0, stream>>>(deg_dst, deg_src, off_dst, cur_dst, off_src, cur_src, N);
  scatter_kernel<<<egrid, 256, 0, stream>>>(src, dst, cur_src, cur_dst, adj_src, pair_dst, E);

  const int total4 = N * HD / 4;
  const int cgrid = (total4 + 255) / 256;
  const int g2 = (N + 127) / 128;  // 128 rows/block (4 waves x 2 tiles x 16)

  qkv_kernel<<<g2, 256, 0, stream>>>(h, wq, bq, wk, bk, wv, bv, q_bf, k_bf, v_bf, N);

  agg_kernel<<<N / 4, 256, 0, stream>>>(h, eattr, off_dst, pair_dst, out_eattr, z_bf, N);
  gemm_kernel<128, 128, 5><<<g2, 256, 0, stream>>>(z_bf, gin_w1, gin_b1, nullptr, mid1, nullptr, 1.0f, N);   // relu, bf16
  gemm_kernel<128, 128, 10><<<g2, 256, 0, stream>>>(mid1, gin_w2, gin_b2, h, X1, sums1, 1.0f, N);            // +h, fp32, stats

  attn_kernel<<<N / 4, 256, 0, stream>>>(q_bf, k_bf, v_bf, off_src, adj_src, h, X2, N);

  stats_kernel<<<256, 256, 0, stream>>>(X2, sums2, sq2, N);
  coeff_kernel<<<1, 128, 0, stream>>>(sums1, sums1 + 128, nl_g, nl_b, ab1, N);
  coeff_kernel<<<1, 128, 0, stream>>>(sums2, sums2 + 128, na_g, na_b, ab2, N);
  combine_kernel<<<cgrid, 256, 0, stream>>>(X1, X2, ab1, ab2, hc_f, total4);

  gemm_kernel<128, 256, 21><<<g2, 256, 0, stream>>>(hc_f, ffn1_w, ffn1_b, nullptr, mid2, nullptr, 1.0f, N);  // fp32 A, relu, bf16
  gemm_kernel<256, 128, 10><<<g2, 256, 0, stream>>>(mid2, ffn2_w, ffn2_b, hc_f, X3, sums3, 1.0f, N);         // +hc, fp32, stats

  coeff_kernel<<<1, 128, 0, stream>>>(sums3, sums3 + 128, no_g, no_b, ab3, N);
  final_kernel<<<cgrid, 256, 0, stream>>>(X3, ab3, out_hc, total4);
}